// Round 1
// baseline (4240.509 us; speedup 1.0000x reference)
//
#include <hip/hip_runtime.h>

#define NN 100000   // nodes
#define EE 800000   // edges
#define BB 4096     // graphs
#define SEQL 1024
#define NODEF 64
#define HH 128
#define LL 3
#define SLOTS 64    // max in-degree slots (Poisson(8): P(deg>40) ~ 1e-30)

__device__ __forceinline__ float f4get(const float4& v, int kk) {
  return kk==0 ? v.x : (kk==1 ? v.y : (kk==2 ? v.z : v.w));
}

// ---------------------------------------------------------------------------
// Pattern A: out[M,128] = LN(relu([x1|x2] @ W + b)) ; threads = columns,
// RT rows per block, x rows staged in LDS (broadcast reads, conflict-free).
// grid.y selects tower (tcr/pep) variant.
// ---------------------------------------------------------------------------
template<int K1, int K2, int RT>
__global__ __launch_bounds__(128) void ln_gemm_A(
    const float* __restrict__ x1a, const float* __restrict__ x1b,
    const float* __restrict__ x2a, const float* __restrict__ x2b,
    const float* __restrict__ Wb, long Wstride,
    const float* __restrict__ bb, const float* __restrict__ gb,
    const float* __restrict__ beb, long pstride,
    float* __restrict__ outa, float* __restrict__ outb)
{
  constexpr int K = K1 + K2;
  constexpr int K4 = K / 4, K14 = K1 / 4;
  const int i = blockIdx.y;
  const float* x1 = i ? x1b : x1a;
  const float* W = Wb + i * Wstride;
  const float* bias = bb + i * pstride;
  const float* g = gb + i * pstride;
  const float* be = beb + i * pstride;
  float* out = i ? outb : outa;

  __shared__ float xs[RT][K];
  __shared__ float red[2][RT][2];
  const int j = threadIdx.x;
  const long r0 = (long)blockIdx.x * RT;

  for (int idx = j; idx < RT * K4; idx += 128) {
    int r = idx / K4, kk = idx % K4;
    float4 v;
    if constexpr (K2 > 0) {
      const float* x2 = i ? x2b : x2a;
      if (kk < K14) v = ((const float4*)(x1 + (r0 + r) * K1))[kk];
      else          v = ((const float4*)(x2 + (r0 + r) * K2))[kk - K14];
    } else {
      v = ((const float4*)(x1 + (r0 + r) * K1))[kk];
    }
    ((float4*)&xs[r][0])[kk] = v;
  }
  __syncthreads();

  float acc[RT];
  #pragma unroll
  for (int r = 0; r < RT; r++) acc[r] = 0.f;

  for (int k4 = 0; k4 < K4; k4++) {
    const int k = k4 * 4;
    float w0 = W[(k + 0) * HH + j];
    float w1 = W[(k + 1) * HH + j];
    float w2 = W[(k + 2) * HH + j];
    float w3 = W[(k + 3) * HH + j];
    #pragma unroll
    for (int r = 0; r < RT; r++) {
      float4 xv = ((const float4*)&xs[r][0])[k4];
      acc[r] = fmaf(xv.x, w0, acc[r]);
      acc[r] = fmaf(xv.y, w1, acc[r]);
      acc[r] = fmaf(xv.z, w2, acc[r]);
      acc[r] = fmaf(xv.w, w3, acc[r]);
    }
  }

  const float bj = bias[j], gj = g[j], bej = be[j];
  float vals[RT], s[RT], q[RT];
  #pragma unroll
  for (int r = 0; r < RT; r++) {
    vals[r] = fmaxf(acc[r] + bj, 0.f);
    float a = vals[r], b2v = a * a;
    #pragma unroll
    for (int off = 32; off >= 1; off >>= 1) {
      a += __shfl_xor(a, off, 64);
      b2v += __shfl_xor(b2v, off, 64);
    }
    s[r] = a; q[r] = b2v;
  }
  const int wv = j >> 6;
  if ((j & 63) == 0) {
    #pragma unroll
    for (int r = 0; r < RT; r++) { red[wv][r][0] = s[r]; red[wv][r][1] = q[r]; }
  }
  __syncthreads();
  #pragma unroll
  for (int r = 0; r < RT; r++) {
    float S = red[0][r][0] + red[1][r][0];
    float Q = red[0][r][1] + red[1][r][1];
    float m = S * (1.f / HH);
    float v = Q * (1.f / HH) - m * m;
    float inv = rsqrtf(fmaxf(v, 0.f) + 1e-5f);
    out[(r0 + r) * HH + j] = (vals[r] - m) * inv * gj + bej;
  }
}

// ---------------------------------------------------------------------------
// Pattern B: thread = row, full 128-wide accumulator in VGPRs, weights via
// wave-uniform (scalar) loads.  gin: h = LN(relu(x @ W + b)), K=64.
// ---------------------------------------------------------------------------
__global__ __launch_bounds__(256, 2) void gin_kernel(
    const float* __restrict__ x, const float* __restrict__ W,
    const float* __restrict__ bias, const float* __restrict__ g,
    const float* __restrict__ be, float* __restrict__ hout)
{
  const int n = blockIdx.x * 256 + threadIdx.x;
  if (n >= NN) return;
  float acc[HH];
  #pragma unroll
  for (int c = 0; c < HH; c++) acc[c] = bias[c];
  const float4* x4 = (const float4*)(x + (long)n * NODEF);
  #pragma unroll 1
  for (int k4 = 0; k4 < NODEF / 4; k4++) {
    float4 xv = x4[k4];
    #pragma unroll
    for (int kk = 0; kk < 4; kk++) {
      const float xk = f4get(xv, kk);
      const float* wr = W + (k4 * 4 + kk) * HH;
      #pragma unroll
      for (int c = 0; c < HH; c++) acc[c] = fmaf(xk, wr[c], acc[c]);
    }
  }
  float s = 0.f, qq = 0.f;
  #pragma unroll
  for (int c = 0; c < HH; c++) {
    float v = fmaxf(acc[c], 0.f); acc[c] = v; s += v; qq = fmaf(v, v, qq);
  }
  float m = s * (1.f / HH), var = qq * (1.f / HH) - m * m;
  float inv = rsqrtf(fmaxf(var, 0.f) + 1e-5f);
  float4* ho = (float4*)(hout + (long)n * HH);
  #pragma unroll
  for (int c4 = 0; c4 < HH / 4; c4++) {
    float4 o;
    o.x = (acc[c4*4+0] - m) * inv * g[c4*4+0] + be[c4*4+0];
    o.y = (acc[c4*4+1] - m) * inv * g[c4*4+1] + be[c4*4+1];
    o.z = (acc[c4*4+2] - m) * inv * g[c4*4+2] + be[c4*4+2];
    o.w = (acc[c4*4+3] - m) * inv * g[c4*4+3] + be[c4*4+3];
    ho[c4] = o;
  }
}

// Layer update: h[n] = LN(relu(h[n]@Wself + bs + agg[n]@Wnei + bn)) — row-local,
// safe in-place on h.
__global__ __launch_bounds__(256, 2) void update_kernel(
    const float* __restrict__ Wself, const float* __restrict__ Wnei,
    const float* __restrict__ bs, const float* __restrict__ bn,
    const float* __restrict__ g, const float* __restrict__ be,
    float* __restrict__ h, const float* __restrict__ agg)
{
  const int n = blockIdx.x * 256 + threadIdx.x;
  if (n >= NN) return;
  float acc[HH];
  #pragma unroll
  for (int c = 0; c < HH; c++) acc[c] = bs[c] + bn[c];
  const float4* h4 = (const float4*)(h + (long)n * HH);
  const float4* a4 = (const float4*)(agg + (long)n * HH);
  #pragma unroll 1
  for (int k4 = 0; k4 < HH / 4; k4++) {
    float4 hv = h4[k4];
    float4 av = a4[k4];
    #pragma unroll
    for (int kk = 0; kk < 4; kk++) {
      const float hk = f4get(hv, kk), ak = f4get(av, kk);
      const float* ws = Wself + (k4 * 4 + kk) * HH;
      const float* wn = Wnei + (k4 * 4 + kk) * HH;
      #pragma unroll
      for (int c = 0; c < HH; c++)
        acc[c] = fmaf(hk, ws[c], fmaf(ak, wn[c], acc[c]));
    }
  }
  float s = 0.f, qq = 0.f;
  #pragma unroll
  for (int c = 0; c < HH; c++) {
    float v = fmaxf(acc[c], 0.f); acc[c] = v; s += v; qq = fmaf(v, v, qq);
  }
  float m = s * (1.f / HH), var = qq * (1.f / HH) - m * m;
  float inv = rsqrtf(fmaxf(var, 0.f) + 1e-5f);
  float4* ho = (float4*)(h + (long)n * HH);
  #pragma unroll
  for (int c4 = 0; c4 < HH / 4; c4++) {
    float4 o;
    o.x = (acc[c4*4+0] - m) * inv * g[c4*4+0] + be[c4*4+0];
    o.y = (acc[c4*4+1] - m) * inv * g[c4*4+1] + be[c4*4+1];
    o.z = (acc[c4*4+2] - m) * inv * g[c4*4+2] + be[c4*4+2];
    o.w = (acc[c4*4+3] - m) * inv * g[c4*4+3] + be[c4*4+3];
    ho[c4] = o;
  }
}

// ---------------------------------------------------------------------------
// Graph structure build (fixed-slot CSR, no scan)
// ---------------------------------------------------------------------------
__global__ void count_kernel(const int* __restrict__ dst, int* __restrict__ cnt) {
  const int e = blockIdx.x * 256 + threadIdx.x;
  if (e < EE) atomicAdd(&cnt[dst[e]], 1);
}

__global__ void invdeg_kernel(const int* __restrict__ cnt, float* __restrict__ invdeg) {
  const int n = blockIdx.x * 256 + threadIdx.x;
  if (n < NN) invdeg[n] = 1.f / fmaxf((float)cnt[n], 1.f);
}

__global__ void fill_kernel(const int* __restrict__ src, const int* __restrict__ dst,
                            int* __restrict__ fil, int* __restrict__ col) {
  const int e = blockIdx.x * 256 + threadIdx.x;
  if (e < EE) {
    int d = dst[e];
    int pos = atomicAdd(&fil[d], 1);
    if (pos < SLOTS) col[(long)d * SLOTS + pos] = src[e];
  }
}

// Mean neighbor aggregation: 2 nodes per block, 128 threads (cols) per node.
// col index is wave-uniform -> scalar load; h row reads coalesced.
__global__ __launch_bounds__(256) void agg_kernel(
    const float* __restrict__ h, const int* __restrict__ col,
    const int* __restrict__ cnt, const float* __restrict__ invdeg,
    float* __restrict__ agg)
{
  const int node = blockIdx.x * 2 + (threadIdx.x >> 7);
  const int j = threadIdx.x & 127;
  const int d = cnt[node];
  const int* cl = col + (long)node * SLOTS;
  float a = 0.f;
  for (int t = 0; t < d; t++) a += h[(long)cl[t] * HH + j];
  agg[(long)node * HH + j] = a * invdeg[node];
}

// Sorted-batch mean pooling: block per graph, binary-search node range.
__global__ __launch_bounds__(128) void pool_kernel(
    const float* __restrict__ h, const int* __restrict__ batch,
    float* __restrict__ pooled)
{
  const int b = blockIdx.x;
  const int j = threadIdx.x;
  int l = 0, r = NN;
  while (l < r) { int mid = (l + r) >> 1; if (batch[mid] < b) l = mid + 1; else r = mid; }
  const int lo = l;
  r = NN;
  while (l < r) { int mid = (l + r) >> 1; if (batch[mid] <= b) l = mid + 1; else r = mid; }
  const int hi = l;
  float s = 0.f;
  for (int n2 = lo; n2 < hi; n2++) s += h[(long)n2 * HH + j];
  pooled[(long)b * HH + j] = s / fmaxf((float)(hi - lo), 1.f);
}

// ---------------------------------------------------------------------------
// Binary head: feat=[tcr,pep,|t-p|,t*p] (512) -> relu(@W1+b1) (256) -> @W2+b2 (2)
// ---------------------------------------------------------------------------
__global__ __launch_bounds__(256) void head_kernel(
    const float* __restrict__ tcr, const float* __restrict__ pep,
    const float* __restrict__ W1, const float* __restrict__ b1,
    const float* __restrict__ W2, const float* __restrict__ b2,
    float* __restrict__ logits)
{
  __shared__ float feat[4][512];
  __shared__ float hid[4][256];
  __shared__ float red[4][4][2];
  const int t = threadIdx.x;
  const long r0 = (long)blockIdx.x * 4;
  for (int idx = t; idx < 4 * 128; idx += 256) {
    int r = idx >> 7, c = idx & 127;
    float a = tcr[(r0 + r) * HH + c], p = pep[(r0 + r) * HH + c];
    feat[r][c] = a; feat[r][128 + c] = p;
    feat[r][256 + c] = fabsf(a - p); feat[r][384 + c] = a * p;
  }
  __syncthreads();
  float acc[4];
  const float b1t = b1[t];
  #pragma unroll
  for (int r = 0; r < 4; r++) acc[r] = b1t;
  for (int k4 = 0; k4 < 128; k4++) {
    const int k = k4 * 4;
    float w0 = W1[(k + 0) * 256 + t], w1v = W1[(k + 1) * 256 + t];
    float w2v = W1[(k + 2) * 256 + t], w3v = W1[(k + 3) * 256 + t];
    #pragma unroll
    for (int r = 0; r < 4; r++) {
      float4 fv = ((const float4*)&feat[r][0])[k4];
      acc[r] = fmaf(fv.x, w0, acc[r]); acc[r] = fmaf(fv.y, w1v, acc[r]);
      acc[r] = fmaf(fv.z, w2v, acc[r]); acc[r] = fmaf(fv.w, w3v, acc[r]);
    }
  }
  #pragma unroll
  for (int r = 0; r < 4; r++) hid[r][t] = fmaxf(acc[r], 0.f);
  __syncthreads();
  const int wv = t >> 6, ln = t & 63;
  float w2c0 = W2[t * 2 + 0], w2c1 = W2[t * 2 + 1];
  #pragma unroll
  for (int r = 0; r < 4; r++) {
    float v0 = hid[r][t] * w2c0, v1 = hid[r][t] * w2c1;
    #pragma unroll
    for (int off = 32; off >= 1; off >>= 1) {
      v0 += __shfl_xor(v0, off, 64);
      v1 += __shfl_xor(v1, off, 64);
    }
    if (ln == 0) { red[wv][r][0] = v0; red[wv][r][1] = v1; }
  }
  __syncthreads();
  if (t < 8) {
    int r = t >> 1, c = t & 1;
    float S = red[0][r][c] + red[1][r][c] + red[2][r][c] + red[3][r][c] + b2[c];
    logits[(r0 + r) * 2 + c] = S;
  }
}

// ---------------------------------------------------------------------------
extern "C" void kernel_launch(void* const* d_in, const int* in_sizes, int n_in,
                              void* d_out, int out_size, void* d_ws, size_t ws_size,
                              hipStream_t stream)
{
  (void)in_sizes; (void)n_in; (void)out_size; (void)ws_size;
  const float* tcr_seq = (const float*)d_in[0];
  const float* pep_seq = (const float*)d_in[1];
  const float* tcr_x   = (const float*)d_in[2];
  const float* pep_x   = (const float*)d_in[3];
  const int*   tcr_edge = (const int*)d_in[4];
  const int*   pep_edge = (const int*)d_in[5];
  const int*   tcr_batch = (const int*)d_in[6];
  const int*   pep_batch = (const int*)d_in[7];
  const float* seq_W  = (const float*)d_in[8];
  const float* seq_b  = (const float*)d_in[9];
  const float* seq_g  = (const float*)d_in[10];
  const float* seq_be = (const float*)d_in[11];
  const float* gin_W  = (const float*)d_in[12];
  const float* gin_b  = (const float*)d_in[13];
  const float* gin_g  = (const float*)d_in[14];
  const float* gin_be = (const float*)d_in[15];
  const float* gl_self_W = (const float*)d_in[16];
  const float* gl_self_b = (const float*)d_in[17];
  const float* gl_nei_W  = (const float*)d_in[18];
  const float* gl_nei_b  = (const float*)d_in[19];
  const float* gl_g  = (const float*)d_in[20];
  const float* gl_be = (const float*)d_in[21];
  const float* gout_W  = (const float*)d_in[22];
  const float* gout_b  = (const float*)d_in[23];
  const float* gout_g  = (const float*)d_in[24];
  const float* gout_be = (const float*)d_in[25];
  const float* fuse_W  = (const float*)d_in[26];
  const float* fuse_b  = (const float*)d_in[27];
  const float* fuse_g  = (const float*)d_in[28];
  const float* fuse_be = (const float*)d_in[29];
  const float* bh_W1 = (const float*)d_in[30];
  const float* bh_b1 = (const float*)d_in[31];
  const float* bh_W2 = (const float*)d_in[32];
  const float* bh_b2 = (const float*)d_in[33];

  float* out = (float*)d_out;
  const long BH = (long)BB * HH;
  float* o_log = out;
  float* o_zts = out + BB * 2;
  float* o_ztg = o_zts + BH;
  float* o_zps = o_ztg + BH;
  float* o_zpg = o_zps + BH;
  float* o_tcr = o_zpg + BH;
  float* o_pep = o_tcr + BH;

  char* w = (char*)d_ws;
  float* buf1   = (float*)w; w += (long)NN * HH * 4;   // h
  float* buf2   = (float*)w; w += (long)NN * HH * 4;   // agg
  float* pooled = (float*)w; w += (long)BB * HH * 4;
  int*   col    = (int*)w;   w += (long)NN * SLOTS * 4;
  int*   cnt    = (int*)w;   w += (long)NN * 4;
  int*   fil    = (int*)w;   w += (long)NN * 4;
  float* invdeg = (float*)w; w += (long)NN * 4;

  // 1. seq towers (both at once via grid.y)
  ln_gemm_A<SEQL, 0, 4><<<dim3(BB / 4, 2), 128, 0, stream>>>(
      tcr_seq, pep_seq, nullptr, nullptr,
      seq_W, (long)SEQL * HH, seq_b, seq_g, seq_be, HH, o_zts, o_zps);

  // 2. graph towers
  for (int i = 0; i < 2; i++) {
    const float* x = i ? pep_x : tcr_x;
    const int* edge = i ? pep_edge : tcr_edge;
    const int* batch = i ? pep_batch : tcr_batch;

    gin_kernel<<<(NN + 255) / 256, 256, 0, stream>>>(
        x, gin_W + (long)i * NODEF * HH,
        gin_b + i * HH, gin_g + i * HH, gin_be + i * HH, buf1);

    hipMemsetAsync(cnt, 0, NN * 4, stream);
    hipMemsetAsync(fil, 0, NN * 4, stream);
    count_kernel<<<EE / 256, 256, 0, stream>>>(edge + EE, cnt);
    invdeg_kernel<<<(NN + 255) / 256, 256, 0, stream>>>(cnt, invdeg);
    fill_kernel<<<EE / 256, 256, 0, stream>>>(edge, edge + EE, fil, col);

    for (int l = 0; l < LL; l++) {
      agg_kernel<<<NN / 2, 256, 0, stream>>>(buf1, col, cnt, invdeg, buf2);
      const long wi = (long)i * LL + l;
      update_kernel<<<(NN + 255) / 256, 256, 0, stream>>>(
          gl_self_W + wi * HH * HH, gl_nei_W + wi * HH * HH,
          gl_self_b + wi * HH, gl_nei_b + wi * HH,
          gl_g + wi * HH, gl_be + wi * HH, buf1, buf2);
    }

    pool_kernel<<<BB, 128, 0, stream>>>(buf1, batch, pooled);

    float* o_zg = i ? o_zpg : o_ztg;
    ln_gemm_A<HH, 0, 4><<<dim3(BB / 4, 1), 128, 0, stream>>>(
        pooled, pooled, nullptr, nullptr,
        gout_W + (long)i * HH * HH, 0,
        gout_b + i * HH, gout_g + i * HH, gout_be + i * HH, 0,
        o_zg, o_zg);
  }

  // 3. fuse towers (both at once)
  ln_gemm_A<HH, HH, 4><<<dim3(BB / 4, 2), 128, 0, stream>>>(
      o_zts, o_zps, o_ztg, o_zpg,
      fuse_W, (long)2 * HH * HH, fuse_b, fuse_g, fuse_be, HH, o_tcr, o_pep);

  // 4. binary head
  head_kernel<<<BB / 4, 256, 0, stream>>>(
      o_tcr, o_pep, bh_W1, bh_b1, bh_W2, bh_b2, o_log);
}

// Round 2
// 1449.797 us; speedup vs baseline: 2.9249x; 2.9249x over previous
//
#include <hip/hip_runtime.h>

#define NN 100000   // nodes
#define EE 800000   // edges
#define BB 4096     // graphs
#define SEQL 1024
#define NODEF 64
#define HH 128
#define LL 3
#define SLOTS 64    // max in-degree slots (Poisson(8): P(deg>40) ~ 1e-30)

typedef __attribute__((ext_vector_type(8))) short bf16x8;
typedef __attribute__((ext_vector_type(4))) float f32x4;

__device__ __forceinline__ float f4get(const float4& v, int kk) {
  return kk==0 ? v.x : (kk==1 ? v.y : (kk==2 ? v.z : v.w));
}
__device__ __forceinline__ float bf2f(short s) {
  union { unsigned u; float f; } x; x.u = ((unsigned)(unsigned short)s) << 16; return x.f;
}
__device__ __forceinline__ short f2bf(float f) {
  union { float f; unsigned u; } x; x.f = f;
  unsigned r = x.u + 0x7FFF + ((x.u >> 16) & 1);
  return (short)(r >> 16);
}

// ---------------------------------------------------------------------------
// Pattern A (f32, small-M GEMMs): out[M,128] = LN(relu([x1|x2] @ W + b))
// threads = columns, RT rows/block, x rows staged in LDS.
// ---------------------------------------------------------------------------
template<int K1, int K2, int RT>
__global__ __launch_bounds__(128) void ln_gemm_A(
    const float* __restrict__ x1a, const float* __restrict__ x1b,
    const float* __restrict__ x2a, const float* __restrict__ x2b,
    const float* __restrict__ Wb, long Wstride,
    const float* __restrict__ bb, const float* __restrict__ gb,
    const float* __restrict__ beb, long pstride,
    float* __restrict__ outa, float* __restrict__ outb)
{
  constexpr int K = K1 + K2;
  constexpr int K4 = K / 4, K14 = K1 / 4;
  const int i = blockIdx.y;
  const float* x1 = i ? x1b : x1a;
  const float* W = Wb + i * Wstride;
  const float* bias = bb + i * pstride;
  const float* g = gb + i * pstride;
  const float* be = beb + i * pstride;
  float* out = i ? outb : outa;

  __shared__ float xs[RT][K];
  __shared__ float red[2][RT][2];
  const int j = threadIdx.x;
  const long r0 = (long)blockIdx.x * RT;

  for (int idx = j; idx < RT * K4; idx += 128) {
    int r = idx / K4, kk = idx % K4;
    float4 v;
    if constexpr (K2 > 0) {
      const float* x2 = i ? x2b : x2a;
      if (kk < K14) v = ((const float4*)(x1 + (r0 + r) * K1))[kk];
      else          v = ((const float4*)(x2 + (r0 + r) * K2))[kk - K14];
    } else {
      v = ((const float4*)(x1 + (r0 + r) * K1))[kk];
    }
    ((float4*)&xs[r][0])[kk] = v;
  }
  __syncthreads();

  float acc[RT];
  #pragma unroll
  for (int r = 0; r < RT; r++) acc[r] = 0.f;

  for (int k4 = 0; k4 < K4; k4++) {
    const int k = k4 * 4;
    float w0 = W[(k + 0) * HH + j];
    float w1 = W[(k + 1) * HH + j];
    float w2 = W[(k + 2) * HH + j];
    float w3 = W[(k + 3) * HH + j];
    #pragma unroll
    for (int r = 0; r < RT; r++) {
      float4 xv = ((const float4*)&xs[r][0])[k4];
      acc[r] = fmaf(xv.x, w0, acc[r]);
      acc[r] = fmaf(xv.y, w1, acc[r]);
      acc[r] = fmaf(xv.z, w2, acc[r]);
      acc[r] = fmaf(xv.w, w3, acc[r]);
    }
  }

  const float bj = bias[j], gj = g[j], bej = be[j];
  float vals[RT], s[RT], q[RT];
  #pragma unroll
  for (int r = 0; r < RT; r++) {
    vals[r] = fmaxf(acc[r] + bj, 0.f);
    float a = vals[r], b2v = a * a;
    #pragma unroll
    for (int off = 32; off >= 1; off >>= 1) {
      a += __shfl_xor(a, off, 64);
      b2v += __shfl_xor(b2v, off, 64);
    }
    s[r] = a; q[r] = b2v;
  }
  const int wv = j >> 6;
  if ((j & 63) == 0) {
    #pragma unroll
    for (int r = 0; r < RT; r++) { red[wv][r][0] = s[r]; red[wv][r][1] = q[r]; }
  }
  __syncthreads();
  #pragma unroll
  for (int r = 0; r < RT; r++) {
    float S = red[0][r][0] + red[1][r][0];
    float Q = red[0][r][1] + red[1][r][1];
    float m = S * (1.f / HH);
    float v = Q * (1.f / HH) - m * m;
    float inv = rsqrtf(fmaxf(v, 0.f) + 1e-5f);
    out[(r0 + r) * HH + j] = (vals[r] - m) * inv * gj + bej;
  }
}

// ---------------------------------------------------------------------------
// Weight packing: B-fragment-friendly [n][k] bf16 layout + combined biases.
// bW_gin[i][n][k] (k<64) ; bW_gl[u][n][k] (k<256: k<128 self, else nei)
// ---------------------------------------------------------------------------
__global__ void pack_kernel(const float* __restrict__ gin_W,
                            const float* __restrict__ gl_self_W,
                            const float* __restrict__ gl_nei_W,
                            const float* __restrict__ gl_self_b,
                            const float* __restrict__ gl_nei_b,
                            short* __restrict__ bW_gin, short* __restrict__ bW_gl,
                            float* __restrict__ biasb)
{
  const int idx = blockIdx.x * 256 + threadIdx.x;
  if (idx < 2 * 128 * 64) {
    int i = idx >> 13, rem = idx & 8191;
    int n = rem >> 6, k = rem & 63;
    bW_gin[idx] = f2bf(gin_W[(long)i * NODEF * HH + k * HH + n]);
  }
  const int j = idx - 2 * 128 * 64;
  if (j >= 0 && j < 6 * 128 * 256) {
    int u = j >> 15, rem = j & 32767;
    int n = rem >> 8, k = rem & 255;
    float v = (k < 128) ? gl_self_W[(long)u * HH * HH + k * HH + n]
                        : gl_nei_W[(long)u * HH * HH + (k - 128) * HH + n];
    bW_gl[j] = f2bf(v);
  }
  if (idx < 6 * 128) biasb[idx] = gl_self_b[idx] + gl_nei_b[idx];
}

// ---------------------------------------------------------------------------
// MFMA GEMM+LN: out[N,128]bf16 = LN(relu(A1@W1 [+ A2@W2] + bias))
// A layout per 16x16x32 bf16: lane holds A[m=lane&15][k=quad*8+j]
// B layout: lane holds W[k=quad*8+j][n=lane&15]  (Wp packed as [n][k])
// D layout: col=lane&15, row=quad*4+reg
// ---------------------------------------------------------------------------
template<int C1, int C2, bool CVT1>
__global__ __launch_bounds__(256) void mfma_ln_kernel(
    const void* __restrict__ A1v, const short* __restrict__ A2,
    const short* __restrict__ Wp, const float* __restrict__ bias,
    const float* __restrict__ g, const float* __restrict__ be,
    short* __restrict__ out, int Nrows)
{
  constexpr int K = (C1 + C2) * 32;
  const int t = threadIdx.x;
  const int lane = t & 63, wv = t >> 6;
  const int m = lane & 15, quad = lane >> 4;
  const int row0 = blockIdx.x * 64 + wv * 16;
  const int r = row0 + m;
  const bool rvalid = (r < Nrows);

  f32x4 acc[8];
  #pragma unroll
  for (int nt = 0; nt < 8; nt++) acc[nt] = (f32x4){0.f, 0.f, 0.f, 0.f};

  #pragma unroll
  for (int c = 0; c < C1 + C2; c++) {
    bf16x8 a = {};
    if (c < C1) {
      if constexpr (CVT1) {
        const float* A1 = (const float*)A1v;
        if (rvalid) {
          const float4* p4 = (const float4*)(A1 + (long)r * (C1 * 32) + c * 32 + quad * 8);
          float4 x0 = p4[0], x1 = p4[1];
          union { bf16x8 v; short s[8]; } u;
          u.s[0] = f2bf(x0.x); u.s[1] = f2bf(x0.y); u.s[2] = f2bf(x0.z); u.s[3] = f2bf(x0.w);
          u.s[4] = f2bf(x1.x); u.s[5] = f2bf(x1.y); u.s[6] = f2bf(x1.z); u.s[7] = f2bf(x1.w);
          a = u.v;
        }
      } else {
        const short* A1 = (const short*)A1v;
        if (rvalid) a = *(const bf16x8*)(A1 + (long)r * (C1 * 32) + c * 32 + quad * 8);
      }
    } else {
      if (rvalid) a = *(const bf16x8*)(A2 + (long)r * (C2 * 32) + (c - C1) * 32 + quad * 8);
    }
    #pragma unroll
    for (int nt = 0; nt < 8; nt++) {
      bf16x8 b = *(const bf16x8*)(Wp + (long)(nt * 16 + m) * K + c * 32 + quad * 8);
      acc[nt] = __builtin_amdgcn_mfma_f32_16x16x32_bf16(a, b, acc[nt], 0, 0, 0);
    }
  }

  // epilogue: bias + relu + LN (rows = quad*4+j, cols = nt*16+m)
  float v[8][4];
  float s[4] = {0.f, 0.f, 0.f, 0.f}, q[4] = {0.f, 0.f, 0.f, 0.f};
  #pragma unroll
  for (int nt = 0; nt < 8; nt++) {
    const float bb = bias[nt * 16 + m];
    #pragma unroll
    for (int j = 0; j < 4; j++) {
      float x = fmaxf(acc[nt][j] + bb, 0.f);
      v[nt][j] = x; s[j] += x; q[j] = fmaf(x, x, q[j]);
    }
  }
  #pragma unroll
  for (int mask = 1; mask <= 8; mask <<= 1) {
    #pragma unroll
    for (int j = 0; j < 4; j++) {
      s[j] += __shfl_xor(s[j], mask, 64);
      q[j] += __shfl_xor(q[j], mask, 64);
    }
  }
  float gj[8], bej[8];
  #pragma unroll
  for (int nt = 0; nt < 8; nt++) { gj[nt] = g[nt * 16 + m]; bej[nt] = be[nt * 16 + m]; }
  #pragma unroll
  for (int j = 0; j < 4; j++) {
    const int row = row0 + quad * 4 + j;
    if (row < Nrows) {
      float mean = s[j] * (1.f / HH);
      float var = q[j] * (1.f / HH) - mean * mean;
      float inv = rsqrtf(fmaxf(var, 0.f) + 1e-5f);
      #pragma unroll
      for (int nt = 0; nt < 8; nt++)
        out[(long)row * HH + nt * 16 + m] = f2bf((v[nt][j] - mean) * inv * gj[nt] + bej[nt]);
    }
  }
}

// ---------------------------------------------------------------------------
// Graph structure build (fixed-slot CSR, no scan)
// ---------------------------------------------------------------------------
__global__ void count_kernel(const int* __restrict__ dst, int* __restrict__ cnt) {
  const int e = blockIdx.x * 256 + threadIdx.x;
  if (e < EE) atomicAdd(&cnt[dst[e]], 1);
}

__global__ void invdeg_kernel(const int* __restrict__ cnt, float* __restrict__ invdeg) {
  const int n = blockIdx.x * 256 + threadIdx.x;
  if (n < NN) invdeg[n] = 1.f / fmaxf((float)cnt[n], 1.f);
}

__global__ void fill_kernel(const int* __restrict__ src, const int* __restrict__ dst,
                            int* __restrict__ fil, int* __restrict__ col) {
  const int e = blockIdx.x * 256 + threadIdx.x;
  if (e < EE) {
    int d = dst[e];
    int pos = atomicAdd(&fil[d], 1);
    if (pos < SLOTS) col[(long)d * SLOTS + pos] = src[e];
  }
}

// Mean neighbor aggregation over bf16 h: one node per wave, 2 cols/lane (4B loads).
__global__ __launch_bounds__(256) void agg_kernel(
    const short* __restrict__ h, const int* __restrict__ col,
    const int* __restrict__ cnt, const float* __restrict__ invdeg,
    short* __restrict__ agg)
{
  const int node = blockIdx.x * 4 + (threadIdx.x >> 6);
  const int lane = threadIdx.x & 63;
  if (node >= NN) return;
  const int d = min(cnt[node], SLOTS);
  const int* cl = col + (long)node * SLOTS;
  float a0 = 0.f, a1 = 0.f;
  for (int tt = 0; tt < d; tt++) {
    unsigned hv = ((const unsigned*)(h + (long)cl[tt] * HH))[lane];
    a0 += bf2f((short)(hv & 0xFFFF));
    a1 += bf2f((short)(hv >> 16));
  }
  const float inv = invdeg[node];
  unsigned o = ((unsigned)(unsigned short)f2bf(a1 * inv) << 16) |
               (unsigned)(unsigned short)f2bf(a0 * inv);
  ((unsigned*)(agg + (long)node * HH))[lane] = o;
}

// Sorted-batch mean pooling over bf16 h: block per graph, binary-search range.
__global__ __launch_bounds__(128) void pool_kernel(
    const short* __restrict__ h, const int* __restrict__ batch,
    float* __restrict__ pooled)
{
  const int b = blockIdx.x;
  const int j = threadIdx.x;
  int l = 0, r = NN;
  while (l < r) { int mid = (l + r) >> 1; if (batch[mid] < b) l = mid + 1; else r = mid; }
  const int lo = l;
  r = NN;
  while (l < r) { int mid = (l + r) >> 1; if (batch[mid] <= b) l = mid + 1; else r = mid; }
  const int hi = l;
  float s = 0.f;
  for (int n2 = lo; n2 < hi; n2++) s += bf2f(h[(long)n2 * HH + j]);
  pooled[(long)b * HH + j] = s / fmaxf((float)(hi - lo), 1.f);
}

// ---------------------------------------------------------------------------
// Binary head: feat=[tcr,pep,|t-p|,t*p] (512) -> relu(@W1+b1) (256) -> @W2+b2
// ---------------------------------------------------------------------------
__global__ __launch_bounds__(256) void head_kernel(
    const float* __restrict__ tcr, const float* __restrict__ pep,
    const float* __restrict__ W1, const float* __restrict__ b1,
    const float* __restrict__ W2, const float* __restrict__ b2,
    float* __restrict__ logits)
{
  __shared__ float feat[4][512];
  __shared__ float hid[4][256];
  __shared__ float red[4][4][2];
  const int t = threadIdx.x;
  const long r0 = (long)blockIdx.x * 4;
  for (int idx = t; idx < 4 * 128; idx += 256) {
    int r = idx >> 7, c = idx & 127;
    float a = tcr[(r0 + r) * HH + c], p = pep[(r0 + r) * HH + c];
    feat[r][c] = a; feat[r][128 + c] = p;
    feat[r][256 + c] = fabsf(a - p); feat[r][384 + c] = a * p;
  }
  __syncthreads();
  float acc[4];
  const float b1t = b1[t];
  #pragma unroll
  for (int r = 0; r < 4; r++) acc[r] = b1t;
  for (int k4 = 0; k4 < 128; k4++) {
    const int k = k4 * 4;
    float w0 = W1[(k + 0) * 256 + t], w1v = W1[(k + 1) * 256 + t];
    float w2v = W1[(k + 2) * 256 + t], w3v = W1[(k + 3) * 256 + t];
    #pragma unroll
    for (int r = 0; r < 4; r++) {
      float4 fv = ((const float4*)&feat[r][0])[k4];
      acc[r] = fmaf(fv.x, w0, acc[r]); acc[r] = fmaf(fv.y, w1v, acc[r]);
      acc[r] = fmaf(fv.z, w2v, acc[r]); acc[r] = fmaf(fv.w, w3v, acc[r]);
    }
  }
  #pragma unroll
  for (int r = 0; r < 4; r++) hid[r][t] = fmaxf(acc[r], 0.f);
  __syncthreads();
  const int wv = t >> 6, ln = t & 63;
  float w2c0 = W2[t * 2 + 0], w2c1 = W2[t * 2 + 1];
  #pragma unroll
  for (int r = 0; r < 4; r++) {
    float v0 = hid[r][t] * w2c0, v1 = hid[r][t] * w2c1;
    #pragma unroll
    for (int off = 32; off >= 1; off >>= 1) {
      v0 += __shfl_xor(v0, off, 64);
      v1 += __shfl_xor(v1, off, 64);
    }
    if (ln == 0) { red[wv][r][0] = v0; red[wv][r][1] = v1; }
  }
  __syncthreads();
  if (t < 8) {
    int r = t >> 1, c = t & 1;
    float S = red[0][r][c] + red[1][r][c] + red[2][r][c] + red[3][r][c] + b2[c];
    logits[(r0 + r) * 2 + c] = S;
  }
}

// ---------------------------------------------------------------------------
extern "C" void kernel_launch(void* const* d_in, const int* in_sizes, int n_in,
                              void* d_out, int out_size, void* d_ws, size_t ws_size,
                              hipStream_t stream)
{
  (void)in_sizes; (void)n_in; (void)out_size; (void)ws_size;
  const float* tcr_seq = (const float*)d_in[0];
  const float* pep_seq = (const float*)d_in[1];
  const float* tcr_x   = (const float*)d_in[2];
  const float* pep_x   = (const float*)d_in[3];
  const int*   tcr_edge = (const int*)d_in[4];
  const int*   pep_edge = (const int*)d_in[5];
  const int*   tcr_batch = (const int*)d_in[6];
  const int*   pep_batch = (const int*)d_in[7];
  const float* seq_W  = (const float*)d_in[8];
  const float* seq_b  = (const float*)d_in[9];
  const float* seq_g  = (const float*)d_in[10];
  const float* seq_be = (const float*)d_in[11];
  const float* gin_W  = (const float*)d_in[12];
  const float* gin_b  = (const float*)d_in[13];
  const float* gin_g  = (const float*)d_in[14];
  const float* gin_be = (const float*)d_in[15];
  const float* gl_self_W = (const float*)d_in[16];
  const float* gl_self_b = (const float*)d_in[17];
  const float* gl_nei_W  = (const float*)d_in[18];
  const float* gl_nei_b  = (const float*)d_in[19];
  const float* gl_g  = (const float*)d_in[20];
  const float* gl_be = (const float*)d_in[21];
  const float* gout_W  = (const float*)d_in[22];
  const float* gout_b  = (const float*)d_in[23];
  const float* gout_g  = (const float*)d_in[24];
  const float* gout_be = (const float*)d_in[25];
  const float* fuse_W  = (const float*)d_in[26];
  const float* fuse_b  = (const float*)d_in[27];
  const float* fuse_g  = (const float*)d_in[28];
  const float* fuse_be = (const float*)d_in[29];
  const float* bh_W1 = (const float*)d_in[30];
  const float* bh_b1 = (const float*)d_in[31];
  const float* bh_W2 = (const float*)d_in[32];
  const float* bh_b2 = (const float*)d_in[33];

  float* out = (float*)d_out;
  const long BH = (long)BB * HH;
  float* o_log = out;
  float* o_zts = out + BB * 2;
  float* o_ztg = o_zts + BH;
  float* o_zps = o_ztg + BH;
  float* o_zpg = o_zps + BH;
  float* o_tcr = o_zpg + BH;
  float* o_pep = o_tcr + BH;

  char* w = (char*)d_ws;
  short* hbuf   = (short*)w; w += (long)NN * HH * 2;   // h (bf16)
  short* abuf   = (short*)w; w += (long)NN * HH * 2;   // agg (bf16)
  int*   col    = (int*)w;   w += (long)NN * SLOTS * 4;
  int*   cnt    = (int*)w;   w += (long)NN * 4;
  int*   fil    = (int*)w;   w += (long)NN * 4;
  float* invdeg = (float*)w; w += (long)NN * 4;
  float* pooled = (float*)w; w += (long)BB * HH * 4;
  short* bW_gin = (short*)w; w += (long)2 * 128 * 64 * 2;
  short* bW_gl  = (short*)w; w += (long)6 * 128 * 256 * 2;
  float* biasb  = (float*)w; w += (long)6 * 128 * 4;

  // 0. pack graph-tower weights to bf16 [n][k] fragments
  pack_kernel<<<(2 * 128 * 64 + 6 * 128 * 256 + 255) / 256, 256, 0, stream>>>(
      gin_W, gl_self_W, gl_nei_W, gl_self_b, gl_nei_b, bW_gin, bW_gl, biasb);

  // 1. seq towers (both at once via grid.y)
  ln_gemm_A<SEQL, 0, 4><<<dim3(BB / 4, 2), 128, 0, stream>>>(
      tcr_seq, pep_seq, nullptr, nullptr,
      seq_W, (long)SEQL * HH, seq_b, seq_g, seq_be, HH, o_zts, o_zps);

  const int GN = (NN + 63) / 64;  // 1563 blocks, 64 rows each

  // 2. graph towers
  for (int i = 0; i < 2; i++) {
    const float* x = i ? pep_x : tcr_x;
    const int* edge = i ? pep_edge : tcr_edge;
    const int* batch = i ? pep_batch : tcr_batch;

    mfma_ln_kernel<2, 0, true><<<GN, 256, 0, stream>>>(
        (const void*)x, nullptr, bW_gin + (long)i * 128 * 64,
        gin_b + i * HH, gin_g + i * HH, gin_be + i * HH, hbuf, NN);

    hipMemsetAsync(cnt, 0, NN * 4, stream);
    hipMemsetAsync(fil, 0, NN * 4, stream);
    count_kernel<<<EE / 256, 256, 0, stream>>>(edge + EE, cnt);
    invdeg_kernel<<<(NN + 255) / 256, 256, 0, stream>>>(cnt, invdeg);
    fill_kernel<<<EE / 256, 256, 0, stream>>>(edge, edge + EE, fil, col);

    for (int l = 0; l < LL; l++) {
      agg_kernel<<<(NN + 3) / 4, 256, 0, stream>>>(hbuf, col, cnt, invdeg, abuf);
      const long wi = (long)i * LL + l;
      mfma_ln_kernel<4, 4, false><<<GN, 256, 0, stream>>>(
          (const void*)hbuf, abuf, bW_gl + wi * 128 * 256,
          biasb + wi * HH, gl_g + wi * HH, gl_be + wi * HH, hbuf, NN);
    }

    pool_kernel<<<BB, 128, 0, stream>>>(hbuf, batch, pooled);

    float* o_zg = i ? o_zpg : o_ztg;
    ln_gemm_A<HH, 0, 4><<<dim3(BB / 4, 1), 128, 0, stream>>>(
        pooled, pooled, nullptr, nullptr,
        gout_W + (long)i * HH * HH, 0,
        gout_b + i * HH, gout_g + i * HH, gout_be + i * HH, 0,
        o_zg, o_zg);
  }

  // 3. fuse towers (both at once)
  ln_gemm_A<HH, HH, 4><<<dim3(BB / 4, 2), 128, 0, stream>>>(
      o_zts, o_zps, o_ztg, o_zpg,
      fuse_W, (long)2 * HH * HH, fuse_b, fuse_g, fuse_be, HH, o_tcr, o_pep);

  // 4. binary head
  head_kernel<<<BB / 4, 256, 0, stream>>>(
      o_tcr, o_pep, bh_W1, bh_b1, bh_W2, bh_b2, o_log);
}

// Round 3
// 1154.199 us; speedup vs baseline: 3.6740x; 1.2561x over previous
//
#include <hip/hip_runtime.h>

#define NN 100000   // nodes
#define EE 800000   // edges
#define BB 4096     // graphs
#define SEQL 1024
#define NODEF 64
#define HH 128
#define LL 3
#define SLOTS 64    // max in-degree slots (Poisson(8): P(deg>40) ~ 1e-30)

typedef __attribute__((ext_vector_type(8))) short bf16x8;
typedef __attribute__((ext_vector_type(4))) float f32x4;

__device__ __forceinline__ float bf2f(short s) {
  union { unsigned u; float f; } x; x.u = ((unsigned)(unsigned short)s) << 16; return x.f;
}
__device__ __forceinline__ short f2bf(float f) {
  union { float f; unsigned u; } x; x.f = f;
  unsigned r = x.u + 0x7FFF + ((x.u >> 16) & 1);
  return (short)(r >> 16);
}
__device__ __forceinline__ float lo16(unsigned v) { return bf2f((short)(v & 0xFFFF)); }
__device__ __forceinline__ float hi16(unsigned v) { return bf2f((short)(v >> 16)); }

// ---------------------------------------------------------------------------
// Pattern A (f32, small-M GEMMs): out[M,128] = LN(relu([x1|x2] @ W + b))
// threads = columns, RT rows/block, x rows staged in LDS.
// ---------------------------------------------------------------------------
template<int K1, int K2, int RT>
__global__ __launch_bounds__(128) void ln_gemm_A(
    const float* __restrict__ x1a, const float* __restrict__ x1b,
    const float* __restrict__ x2a, const float* __restrict__ x2b,
    const float* __restrict__ Wb, long Wstride,
    const float* __restrict__ bb, const float* __restrict__ gb,
    const float* __restrict__ beb, long pstride,
    float* __restrict__ outa, float* __restrict__ outb)
{
  constexpr int K = K1 + K2;
  constexpr int K4 = K / 4, K14 = K1 / 4;
  const int i = blockIdx.y;
  const float* x1 = i ? x1b : x1a;
  const float* W = Wb + i * Wstride;
  const float* bias = bb + i * pstride;
  const float* g = gb + i * pstride;
  const float* be = beb + i * pstride;
  float* out = i ? outb : outa;

  __shared__ float xs[RT][K];
  __shared__ float red[2][RT][2];
  const int j = threadIdx.x;
  const long r0 = (long)blockIdx.x * RT;

  for (int idx = j; idx < RT * K4; idx += 128) {
    int r = idx / K4, kk = idx % K4;
    float4 v;
    if constexpr (K2 > 0) {
      const float* x2 = i ? x2b : x2a;
      if (kk < K14) v = ((const float4*)(x1 + (r0 + r) * K1))[kk];
      else          v = ((const float4*)(x2 + (r0 + r) * K2))[kk - K14];
    } else {
      v = ((const float4*)(x1 + (r0 + r) * K1))[kk];
    }
    ((float4*)&xs[r][0])[kk] = v;
  }
  __syncthreads();

  float acc[RT];
  #pragma unroll
  for (int r = 0; r < RT; r++) acc[r] = 0.f;

  for (int k4 = 0; k4 < K4; k4++) {
    const int k = k4 * 4;
    float w0 = W[(k + 0) * HH + j];
    float w1 = W[(k + 1) * HH + j];
    float w2 = W[(k + 2) * HH + j];
    float w3 = W[(k + 3) * HH + j];
    #pragma unroll
    for (int r = 0; r < RT; r++) {
      float4 xv = ((const float4*)&xs[r][0])[k4];
      acc[r] = fmaf(xv.x, w0, acc[r]);
      acc[r] = fmaf(xv.y, w1, acc[r]);
      acc[r] = fmaf(xv.z, w2, acc[r]);
      acc[r] = fmaf(xv.w, w3, acc[r]);
    }
  }

  const float bj = bias[j], gj = g[j], bej = be[j];
  float vals[RT], s[RT], q[RT];
  #pragma unroll
  for (int r = 0; r < RT; r++) {
    vals[r] = fmaxf(acc[r] + bj, 0.f);
    float a = vals[r], b2v = a * a;
    #pragma unroll
    for (int off = 32; off >= 1; off >>= 1) {
      a += __shfl_xor(a, off, 64);
      b2v += __shfl_xor(b2v, off, 64);
    }
    s[r] = a; q[r] = b2v;
  }
  const int wv = j >> 6;
  if ((j & 63) == 0) {
    #pragma unroll
    for (int r = 0; r < RT; r++) { red[wv][r][0] = s[r]; red[wv][r][1] = q[r]; }
  }
  __syncthreads();
  #pragma unroll
  for (int r = 0; r < RT; r++) {
    float S = red[0][r][0] + red[1][r][0];
    float Q = red[0][r][1] + red[1][r][1];
    float m = S * (1.f / HH);
    float v = Q * (1.f / HH) - m * m;
    float inv = rsqrtf(fmaxf(v, 0.f) + 1e-5f);
    out[(r0 + r) * HH + j] = (vals[r] - m) * inv * gj + bej;
  }
}

// ---------------------------------------------------------------------------
// Weight packing: B-fragment-friendly [n][k] bf16 layout + combined biases.
// ---------------------------------------------------------------------------
__global__ void pack_kernel(const float* __restrict__ gin_W,
                            const float* __restrict__ gl_self_W,
                            const float* __restrict__ gl_nei_W,
                            const float* __restrict__ gl_self_b,
                            const float* __restrict__ gl_nei_b,
                            short* __restrict__ bW_gin, short* __restrict__ bW_gl,
                            float* __restrict__ biasb)
{
  const int idx = blockIdx.x * 256 + threadIdx.x;
  if (idx < 2 * 128 * 64) {
    int i = idx >> 13, rem = idx & 8191;
    int n = rem >> 6, k = rem & 63;
    bW_gin[idx] = f2bf(gin_W[(long)i * NODEF * HH + k * HH + n]);
  }
  const int j = idx - 2 * 128 * 64;
  if (j >= 0 && j < 6 * 128 * 256) {
    int u = j >> 15, rem = j & 32767;
    int n = rem >> 8, k = rem & 255;
    float v = (k < 128) ? gl_self_W[(long)u * HH * HH + k * HH + n]
                        : gl_nei_W[(long)u * HH * HH + (k - 128) * HH + n];
    bW_gl[j] = f2bf(v);
  }
  if (idx < 6 * 128) biasb[idx] = gl_self_b[idx] + gl_nei_b[idx];
}

// ---------------------------------------------------------------------------
// MFMA GEMM+LN: out[N,128]bf16 = LN(relu(A1@W1 [+ A2@W2] + bias))
// ---------------------------------------------------------------------------
template<int C1, int C2, bool CVT1>
__global__ __launch_bounds__(256) void mfma_ln_kernel(
    const void* __restrict__ A1v, const short* __restrict__ A2,
    const short* __restrict__ Wp, const float* __restrict__ bias,
    const float* __restrict__ g, const float* __restrict__ be,
    short* __restrict__ out, int Nrows)
{
  constexpr int K = (C1 + C2) * 32;
  const int t = threadIdx.x;
  const int lane = t & 63, wv = t >> 6;
  const int m = lane & 15, quad = lane >> 4;
  const int row0 = blockIdx.x * 64 + wv * 16;
  const int r = row0 + m;
  const bool rvalid = (r < Nrows);

  f32x4 acc[8];
  #pragma unroll
  for (int nt = 0; nt < 8; nt++) acc[nt] = (f32x4){0.f, 0.f, 0.f, 0.f};

  #pragma unroll
  for (int c = 0; c < C1 + C2; c++) {
    bf16x8 a = {};
    if (c < C1) {
      if constexpr (CVT1) {
        const float* A1 = (const float*)A1v;
        if (rvalid) {
          const float4* p4 = (const float4*)(A1 + (long)r * (C1 * 32) + c * 32 + quad * 8);
          float4 x0 = p4[0], x1 = p4[1];
          union { bf16x8 v; short s[8]; } u;
          u.s[0] = f2bf(x0.x); u.s[1] = f2bf(x0.y); u.s[2] = f2bf(x0.z); u.s[3] = f2bf(x0.w);
          u.s[4] = f2bf(x1.x); u.s[5] = f2bf(x1.y); u.s[6] = f2bf(x1.z); u.s[7] = f2bf(x1.w);
          a = u.v;
        }
      } else {
        const short* A1 = (const short*)A1v;
        if (rvalid) a = *(const bf16x8*)(A1 + (long)r * (C1 * 32) + c * 32 + quad * 8);
      }
    } else {
      if (rvalid) a = *(const bf16x8*)(A2 + (long)r * (C2 * 32) + (c - C1) * 32 + quad * 8);
    }
    #pragma unroll
    for (int nt = 0; nt < 8; nt++) {
      bf16x8 b = *(const bf16x8*)(Wp + (long)(nt * 16 + m) * K + c * 32 + quad * 8);
      acc[nt] = __builtin_amdgcn_mfma_f32_16x16x32_bf16(a, b, acc[nt], 0, 0, 0);
    }
  }

  // epilogue: bias + relu + LN (rows = quad*4+j, cols = nt*16+m)
  float v[8][4];
  float s[4] = {0.f, 0.f, 0.f, 0.f}, q[4] = {0.f, 0.f, 0.f, 0.f};
  #pragma unroll
  for (int nt = 0; nt < 8; nt++) {
    const float bb = bias[nt * 16 + m];
    #pragma unroll
    for (int j = 0; j < 4; j++) {
      float x = fmaxf(acc[nt][j] + bb, 0.f);
      v[nt][j] = x; s[j] += x; q[j] = fmaf(x, x, q[j]);
    }
  }
  #pragma unroll
  for (int mask = 1; mask <= 8; mask <<= 1) {
    #pragma unroll
    for (int j = 0; j < 4; j++) {
      s[j] += __shfl_xor(s[j], mask, 64);
      q[j] += __shfl_xor(q[j], mask, 64);
    }
  }
  float gj[8], bej[8];
  #pragma unroll
  for (int nt = 0; nt < 8; nt++) { gj[nt] = g[nt * 16 + m]; bej[nt] = be[nt * 16 + m]; }
  #pragma unroll
  for (int j = 0; j < 4; j++) {
    const int row = row0 + quad * 4 + j;
    if (row < Nrows) {
      float mean = s[j] * (1.f / HH);
      float var = q[j] * (1.f / HH) - mean * mean;
      float inv = rsqrtf(fmaxf(var, 0.f) + 1e-5f);
      #pragma unroll
      for (int nt = 0; nt < 8; nt++)
        out[(long)row * HH + nt * 16 + m] = f2bf((v[nt][j] - mean) * inv * gj[nt] + bej[nt]);
    }
  }
}

// ---------------------------------------------------------------------------
// Graph structure build: fill computes degrees via atomicAdd return values.
// ---------------------------------------------------------------------------
__global__ void fill_kernel(const int* __restrict__ src, const int* __restrict__ dst,
                            int* __restrict__ fil, int* __restrict__ col) {
  const int e = blockIdx.x * 256 + threadIdx.x;
  if (e < EE) {
    int d = dst[e];
    int pos = atomicAdd(&fil[d], 1);
    if (pos < SLOTS) col[(long)d * SLOTS + pos] = src[e];
  }
}

__global__ void invdeg_kernel(const int* __restrict__ cnt, float* __restrict__ invdeg) {
  const int n = blockIdx.x * 256 + threadIdx.x;
  if (n < NN) invdeg[n] = 1.f / fmaxf((float)cnt[n], 1.f);
}

// Mean neighbor aggregation over bf16 h: one node per wave, 2 cols/lane,
// 8-deep manual unroll for memory-level parallelism (gather is L3-latency).
__global__ __launch_bounds__(256) void agg_kernel(
    const short* __restrict__ h, const int* __restrict__ col,
    const int* __restrict__ cnt, const float* __restrict__ invdeg,
    short* __restrict__ agg)
{
  const int node = blockIdx.x * 4 + (threadIdx.x >> 6);
  const int lane = threadIdx.x & 63;
  if (node >= NN) return;
  const int d = min(cnt[node], SLOTS);
  const int* cl = col + (long)node * SLOTS;
  const unsigned* h32 = (const unsigned*)h;

  float s0 = 0.f, s1 = 0.f, t0 = 0.f, t1 = 0.f;
  float u0 = 0.f, u1 = 0.f, w0 = 0.f, w1 = 0.f;
  int t = 0;
  for (; t + 8 <= d; t += 8) {
    int4 i0 = *(const int4*)(cl + t);
    int4 i1 = *(const int4*)(cl + t + 4);
    unsigned v0 = h32[(long)i0.x * 64 + lane];
    unsigned v1 = h32[(long)i0.y * 64 + lane];
    unsigned v2 = h32[(long)i0.z * 64 + lane];
    unsigned v3 = h32[(long)i0.w * 64 + lane];
    unsigned v4 = h32[(long)i1.x * 64 + lane];
    unsigned v5 = h32[(long)i1.y * 64 + lane];
    unsigned v6 = h32[(long)i1.z * 64 + lane];
    unsigned v7 = h32[(long)i1.w * 64 + lane];
    s0 += lo16(v0); s1 += hi16(v0);
    t0 += lo16(v1); t1 += hi16(v1);
    u0 += lo16(v2); u1 += hi16(v2);
    w0 += lo16(v3); w1 += hi16(v3);
    s0 += lo16(v4); s1 += hi16(v4);
    t0 += lo16(v5); t1 += hi16(v5);
    u0 += lo16(v6); u1 += hi16(v6);
    w0 += lo16(v7); w1 += hi16(v7);
  }
  if (t + 4 <= d) {
    int4 i0 = *(const int4*)(cl + t);
    unsigned v0 = h32[(long)i0.x * 64 + lane];
    unsigned v1 = h32[(long)i0.y * 64 + lane];
    unsigned v2 = h32[(long)i0.z * 64 + lane];
    unsigned v3 = h32[(long)i0.w * 64 + lane];
    s0 += lo16(v0); s1 += hi16(v0);
    t0 += lo16(v1); t1 += hi16(v1);
    u0 += lo16(v2); u1 += hi16(v2);
    w0 += lo16(v3); w1 += hi16(v3);
    t += 4;
  }
  for (; t < d; t++) {
    unsigned v0 = h32[(long)cl[t] * 64 + lane];
    s0 += lo16(v0); s1 += hi16(v0);
  }
  float a0 = (s0 + t0) + (u0 + w0);
  float a1 = (s1 + t1) + (u1 + w1);
  const float inv = invdeg[node];
  unsigned o = ((unsigned)(unsigned short)f2bf(a1 * inv) << 16) |
               (unsigned)(unsigned short)f2bf(a0 * inv);
  ((unsigned*)(agg + (long)node * HH))[lane] = o;
}

// Sorted-batch mean pooling over bf16 h: block per graph, binary-search range.
__global__ __launch_bounds__(128) void pool_kernel(
    const short* __restrict__ h, const int* __restrict__ batch,
    float* __restrict__ pooled)
{
  const int b = blockIdx.x;
  const int j = threadIdx.x;
  int l = 0, r = NN;
  while (l < r) { int mid = (l + r) >> 1; if (batch[mid] < b) l = mid + 1; else r = mid; }
  const int lo = l;
  r = NN;
  while (l < r) { int mid = (l + r) >> 1; if (batch[mid] <= b) l = mid + 1; else r = mid; }
  const int hi = l;
  float s = 0.f;
  for (int n2 = lo; n2 < hi; n2++) s += bf2f(h[(long)n2 * HH + j]);
  pooled[(long)b * HH + j] = s / fmaxf((float)(hi - lo), 1.f);
}

// ---------------------------------------------------------------------------
// Binary head: feat=[tcr,pep,|t-p|,t*p] (512) -> relu(@W1+b1) (256) -> @W2+b2
// ---------------------------------------------------------------------------
__global__ __launch_bounds__(256) void head_kernel(
    const float* __restrict__ tcr, const float* __restrict__ pep,
    const float* __restrict__ W1, const float* __restrict__ b1,
    const float* __restrict__ W2, const float* __restrict__ b2,
    float* __restrict__ logits)
{
  __shared__ float feat[4][512];
  __shared__ float hid[4][256];
  __shared__ float red[4][4][2];
  const int t = threadIdx.x;
  const long r0 = (long)blockIdx.x * 4;
  for (int idx = t; idx < 4 * 128; idx += 256) {
    int r = idx >> 7, c = idx & 127;
    float a = tcr[(r0 + r) * HH + c], p = pep[(r0 + r) * HH + c];
    feat[r][c] = a; feat[r][128 + c] = p;
    feat[r][256 + c] = fabsf(a - p); feat[r][384 + c] = a * p;
  }
  __syncthreads();
  float acc[4];
  const float b1t = b1[t];
  #pragma unroll
  for (int r = 0; r < 4; r++) acc[r] = b1t;
  for (int k4 = 0; k4 < 128; k4++) {
    const int k = k4 * 4;
    float w0 = W1[(k + 0) * 256 + t], w1v = W1[(k + 1) * 256 + t];
    float w2v = W1[(k + 2) * 256 + t], w3v = W1[(k + 3) * 256 + t];
    #pragma unroll
    for (int r = 0; r < 4; r++) {
      float4 fv = ((const float4*)&feat[r][0])[k4];
      acc[r] = fmaf(fv.x, w0, acc[r]); acc[r] = fmaf(fv.y, w1v, acc[r]);
      acc[r] = fmaf(fv.z, w2v, acc[r]); acc[r] = fmaf(fv.w, w3v, acc[r]);
    }
  }
  #pragma unroll
  for (int r = 0; r < 4; r++) hid[r][t] = fmaxf(acc[r], 0.f);
  __syncthreads();
  const int wv = t >> 6, ln = t & 63;
  float w2c0 = W2[t * 2 + 0], w2c1 = W2[t * 2 + 1];
  #pragma unroll
  for (int r = 0; r < 4; r++) {
    float v0 = hid[r][t] * w2c0, v1 = hid[r][t] * w2c1;
    #pragma unroll
    for (int off = 32; off >= 1; off >>= 1) {
      v0 += __shfl_xor(v0, off, 64);
      v1 += __shfl_xor(v1, off, 64);
    }
    if (ln == 0) { red[wv][r][0] = v0; red[wv][r][1] = v1; }
  }
  __syncthreads();
  if (t < 8) {
    int r = t >> 1, c = t & 1;
    float S = red[0][r][c] + red[1][r][c] + red[2][r][c] + red[3][r][c] + b2[c];
    logits[(r0 + r) * 2 + c] = S;
  }
}

// ---------------------------------------------------------------------------
extern "C" void kernel_launch(void* const* d_in, const int* in_sizes, int n_in,
                              void* d_out, int out_size, void* d_ws, size_t ws_size,
                              hipStream_t stream)
{
  (void)in_sizes; (void)n_in; (void)out_size; (void)ws_size;
  const float* tcr_seq = (const float*)d_in[0];
  const float* pep_seq = (const float*)d_in[1];
  const float* tcr_x   = (const float*)d_in[2];
  const float* pep_x   = (const float*)d_in[3];
  const int*   tcr_edge = (const int*)d_in[4];
  const int*   pep_edge = (const int*)d_in[5];
  const int*   tcr_batch = (const int*)d_in[6];
  const int*   pep_batch = (const int*)d_in[7];
  const float* seq_W  = (const float*)d_in[8];
  const float* seq_b  = (const float*)d_in[9];
  const float* seq_g  = (const float*)d_in[10];
  const float* seq_be = (const float*)d_in[11];
  const float* gin_W  = (const float*)d_in[12];
  const float* gin_b  = (const float*)d_in[13];
  const float* gin_g  = (const float*)d_in[14];
  const float* gin_be = (const float*)d_in[15];
  const float* gl_self_W = (const float*)d_in[16];
  const float* gl_self_b = (const float*)d_in[17];
  const float* gl_nei_W  = (const float*)d_in[18];
  const float* gl_nei_b  = (const float*)d_in[19];
  const float* gl_g  = (const float*)d_in[20];
  const float* gl_be = (const float*)d_in[21];
  const float* gout_W  = (const float*)d_in[22];
  const float* gout_b  = (const float*)d_in[23];
  const float* gout_g  = (const float*)d_in[24];
  const float* gout_be = (const float*)d_in[25];
  const float* fuse_W  = (const float*)d_in[26];
  const float* fuse_b  = (const float*)d_in[27];
  const float* fuse_g  = (const float*)d_in[28];
  const float* fuse_be = (const float*)d_in[29];
  const float* bh_W1 = (const float*)d_in[30];
  const float* bh_b1 = (const float*)d_in[31];
  const float* bh_W2 = (const float*)d_in[32];
  const float* bh_b2 = (const float*)d_in[33];

  float* out = (float*)d_out;
  const long BH = (long)BB * HH;
  float* o_log = out;
  float* o_zts = out + BB * 2;
  float* o_ztg = o_zts + BH;
  float* o_zps = o_ztg + BH;
  float* o_zpg = o_zps + BH;
  float* o_tcr = o_zpg + BH;
  float* o_pep = o_tcr + BH;

  char* w = (char*)d_ws;
  short* hbuf   = (short*)w; w += (long)NN * HH * 2;   // h (bf16)
  short* abuf   = (short*)w; w += (long)NN * HH * 2;   // agg (bf16)
  int*   col    = (int*)w;   w += (long)NN * SLOTS * 4;
  int*   fil    = (int*)w;   w += (long)NN * 4;        // becomes degree
  float* invdeg = (float*)w; w += (long)NN * 4;
  float* pooled = (float*)w; w += (long)BB * HH * 4;
  short* bW_gin = (short*)w; w += (long)2 * 128 * 64 * 2;
  short* bW_gl  = (short*)w; w += (long)6 * 128 * 256 * 2;
  float* biasb  = (float*)w; w += (long)6 * 128 * 4;

  // 0. pack graph-tower weights to bf16 [n][k] fragments
  pack_kernel<<<(2 * 128 * 64 + 6 * 128 * 256 + 255) / 256, 256, 0, stream>>>(
      gin_W, gl_self_W, gl_nei_W, gl_self_b, gl_nei_b, bW_gin, bW_gl, biasb);

  // 1. seq towers (both at once via grid.y)
  ln_gemm_A<SEQL, 0, 8><<<dim3(BB / 8, 2), 128, 0, stream>>>(
      tcr_seq, pep_seq, nullptr, nullptr,
      seq_W, (long)SEQL * HH, seq_b, seq_g, seq_be, HH, o_zts, o_zps);

  const int GN = (NN + 63) / 64;

  // 2. graph towers
  for (int i = 0; i < 2; i++) {
    const float* x = i ? pep_x : tcr_x;
    const int* edge = i ? pep_edge : tcr_edge;
    const int* batch = i ? pep_batch : tcr_batch;

    mfma_ln_kernel<2, 0, true><<<GN, 256, 0, stream>>>(
        (const void*)x, nullptr, bW_gin + (long)i * 128 * 64,
        gin_b + i * HH, gin_g + i * HH, gin_be + i * HH, hbuf, NN);

    hipMemsetAsync(fil, 0, NN * 4, stream);
    fill_kernel<<<EE / 256, 256, 0, stream>>>(edge, edge + EE, fil, col);
    invdeg_kernel<<<(NN + 255) / 256, 256, 0, stream>>>(fil, invdeg);

    for (int l = 0; l < LL; l++) {
      agg_kernel<<<(NN + 3) / 4, 256, 0, stream>>>(hbuf, col, fil, invdeg, abuf);
      const long wi = (long)i * LL + l;
      mfma_ln_kernel<4, 4, false><<<GN, 256, 0, stream>>>(
          (const void*)hbuf, abuf, bW_gl + wi * 128 * 256,
          biasb + wi * HH, gl_g + wi * HH, gl_be + wi * HH, hbuf, NN);
    }

    pool_kernel<<<BB, 128, 0, stream>>>(hbuf, batch, pooled);

    float* o_zg = i ? o_zpg : o_ztg;
    ln_gemm_A<HH, 0, 8><<<dim3(BB / 8, 1), 128, 0, stream>>>(
        pooled, pooled, nullptr, nullptr,
        gout_W + (long)i * HH * HH, 0,
        gout_b + i * HH, gout_g + i * HH, gout_be + i * HH, 0,
        o_zg, o_zg);
  }

  // 3. fuse towers (both at once)
  ln_gemm_A<HH, HH, 8><<<dim3(BB / 8, 2), 128, 0, stream>>>(
      o_zts, o_zps, o_ztg, o_zpg,
      fuse_W, (long)2 * HH * HH, fuse_b, fuse_g, fuse_be, HH, o_tcr, o_pep);

  // 4. binary head
  head_kernel<<<BB / 4, 256, 0, stream>>>(
      o_tcr, o_pep, bh_W1, bh_b1, bh_W2, bh_b2, o_log);
}

// Round 4
// 985.805 us; speedup vs baseline: 4.3016x; 1.1708x over previous
//
#include <hip/hip_runtime.h>

#define NN 100000   // nodes
#define EE 800000   // edges
#define BB 4096     // graphs
#define SEQL 1024
#define NODEF 64
#define HH 128
#define LL 3
#define SLOTS 64    // max in-degree slots (Poisson(8): P(deg>40) ~ 1e-30)

typedef __attribute__((ext_vector_type(8))) short bf16x8;
typedef __attribute__((ext_vector_type(4))) float f32x4;

__device__ __forceinline__ float bf2f(short s) {
  union { unsigned u; float f; } x; x.u = ((unsigned)(unsigned short)s) << 16; return x.f;
}
__device__ __forceinline__ short f2bf(float f) {
  union { float f; unsigned u; } x; x.f = f;
  unsigned r = x.u + 0x7FFF + ((x.u >> 16) & 1);
  return (short)(r >> 16);
}
__device__ __forceinline__ float lo16(unsigned v) { return bf2f((short)(v & 0xFFFF)); }
__device__ __forceinline__ float hi16(unsigned v) { return bf2f((short)(v >> 16)); }

// ---------------------------------------------------------------------------
// Pattern A (f32, small-M GEMMs): out[M,128] = LN(relu([x1|x2] @ W + b))
// threads = columns, RT rows/block, x rows staged in LDS. grid.y = tower.
// ---------------------------------------------------------------------------
template<int K1, int K2, int RT>
__global__ __launch_bounds__(128) void ln_gemm_A(
    const float* __restrict__ x1a, const float* __restrict__ x1b,
    const float* __restrict__ x2a, const float* __restrict__ x2b,
    const float* __restrict__ Wb, long Wstride,
    const float* __restrict__ bb, const float* __restrict__ gb,
    const float* __restrict__ beb, long pstride,
    float* __restrict__ outa, float* __restrict__ outb)
{
  constexpr int K = K1 + K2;
  constexpr int K4 = K / 4, K14 = K1 / 4;
  const int i = blockIdx.y;
  const float* x1 = i ? x1b : x1a;
  const float* W = Wb + i * Wstride;
  const float* bias = bb + i * pstride;
  const float* g = gb + i * pstride;
  const float* be = beb + i * pstride;
  float* out = i ? outb : outa;

  __shared__ float xs[RT][K];
  __shared__ float red[2][RT][2];
  const int j = threadIdx.x;
  const long r0 = (long)blockIdx.x * RT;

  for (int idx = j; idx < RT * K4; idx += 128) {
    int r = idx / K4, kk = idx % K4;
    float4 v;
    if constexpr (K2 > 0) {
      const float* x2 = i ? x2b : x2a;
      if (kk < K14) v = ((const float4*)(x1 + (r0 + r) * K1))[kk];
      else          v = ((const float4*)(x2 + (r0 + r) * K2))[kk - K14];
    } else {
      v = ((const float4*)(x1 + (r0 + r) * K1))[kk];
    }
    ((float4*)&xs[r][0])[kk] = v;
  }
  __syncthreads();

  float acc[RT];
  #pragma unroll
  for (int r = 0; r < RT; r++) acc[r] = 0.f;

  for (int k4 = 0; k4 < K4; k4++) {
    const int k = k4 * 4;
    float w0 = W[(k + 0) * HH + j];
    float w1 = W[(k + 1) * HH + j];
    float w2 = W[(k + 2) * HH + j];
    float w3 = W[(k + 3) * HH + j];
    #pragma unroll
    for (int r = 0; r < RT; r++) {
      float4 xv = ((const float4*)&xs[r][0])[k4];
      acc[r] = fmaf(xv.x, w0, acc[r]);
      acc[r] = fmaf(xv.y, w1, acc[r]);
      acc[r] = fmaf(xv.z, w2, acc[r]);
      acc[r] = fmaf(xv.w, w3, acc[r]);
    }
  }

  const float bj = bias[j], gj = g[j], bej = be[j];
  float vals[RT], s[RT], q[RT];
  #pragma unroll
  for (int r = 0; r < RT; r++) {
    vals[r] = fmaxf(acc[r] + bj, 0.f);
    float a = vals[r], b2v = a * a;
    #pragma unroll
    for (int off = 32; off >= 1; off >>= 1) {
      a += __shfl_xor(a, off, 64);
      b2v += __shfl_xor(b2v, off, 64);
    }
    s[r] = a; q[r] = b2v;
  }
  const int wv = j >> 6;
  if ((j & 63) == 0) {
    #pragma unroll
    for (int r = 0; r < RT; r++) { red[wv][r][0] = s[r]; red[wv][r][1] = q[r]; }
  }
  __syncthreads();
  #pragma unroll
  for (int r = 0; r < RT; r++) {
    float S = red[0][r][0] + red[1][r][0];
    float Q = red[0][r][1] + red[1][r][1];
    float m = S * (1.f / HH);
    float v = Q * (1.f / HH) - m * m;
    float inv = rsqrtf(fmaxf(v, 0.f) + 1e-5f);
    out[(r0 + r) * HH + j] = (vals[r] - m) * inv * gj + bej;
  }
}

// ---------------------------------------------------------------------------
// Weight packing to bf16 [n][k] B-fragment layout + combined biases.
// seq: 2*128*1024 ; gin: 2*128*64 ; gl: 6*128*256 ; biasb: 6*128
// ---------------------------------------------------------------------------
#define SEQ_ELEMS (2 * 128 * 1024)
#define GIN_ELEMS (2 * 128 * 64)
#define GL_ELEMS  (6 * 128 * 256)

__global__ void pack_kernel(const float* __restrict__ seq_W,
                            const float* __restrict__ gin_W,
                            const float* __restrict__ gl_self_W,
                            const float* __restrict__ gl_nei_W,
                            const float* __restrict__ gl_self_b,
                            const float* __restrict__ gl_nei_b,
                            short* __restrict__ bW_seq,
                            short* __restrict__ bW_gin, short* __restrict__ bW_gl,
                            float* __restrict__ biasb)
{
  const int idx = blockIdx.x * 256 + threadIdx.x;
  if (idx < SEQ_ELEMS) {
    int i = idx >> 17, rem = idx & 131071;
    int n = rem >> 10, k = rem & 1023;
    bW_seq[idx] = f2bf(seq_W[(long)i * SEQL * HH + (long)k * HH + n]);
  }
  const int j = idx - SEQ_ELEMS;
  if (j >= 0 && j < GIN_ELEMS) {
    int i = j >> 13, rem = j & 8191;
    int n = rem >> 6, k = rem & 63;
    bW_gin[j] = f2bf(gin_W[(long)i * NODEF * HH + k * HH + n]);
  }
  const int j2 = idx - SEQ_ELEMS - GIN_ELEMS;
  if (j2 >= 0 && j2 < GL_ELEMS) {
    int u = j2 >> 15, rem = j2 & 32767;
    int n = rem >> 8, k = rem & 255;
    float v = (k < 128) ? gl_self_W[(long)u * HH * HH + k * HH + n]
                        : gl_nei_W[(long)u * HH * HH + (k - 128) * HH + n];
    bW_gl[j2] = f2bf(v);
  }
  if (idx < 6 * 128) biasb[idx] = gl_self_b[idx] + gl_nei_b[idx];
}

// ---------------------------------------------------------------------------
// MFMA GEMM+LN: out[N,128] = LN(relu(A1@W1 [+ A2@W2] + bias))
// grid.y = tower. RPW row-tiles per wave (B-fragment reuse).
// A frag (16x16x32 bf16): lane holds A[m=lane&15][k=quad*8+j]
// B frag: lane holds W[k=quad*8+j][n=lane&15]   (Wp packed [n][k])
// D frag: col=lane&15, row=quad*4+reg
// ---------------------------------------------------------------------------
template<int C1, int C2, bool CVT1, bool F32OUT, int RPW>
__global__ __launch_bounds__(256) void mfma_ln_k(
    const void* __restrict__ A1a, const void* __restrict__ A1b,
    const short* __restrict__ A2, long A2twr,
    const short* __restrict__ Wp, long Wtwr,
    const float* __restrict__ bias, const float* __restrict__ g,
    const float* __restrict__ be, long Ptwr,
    void* __restrict__ outa, void* __restrict__ outb, long Otwr,
    int Nrows)
{
  constexpr int K = (C1 + C2) * 32;
  const int i = blockIdx.y;
  const void* A1 = i ? A1b : A1a;
  const short* A2p = A2 + i * A2twr;
  const short* Wq = Wp + i * Wtwr;
  const float* bi = bias + i * Ptwr;
  const float* gi = g + i * Ptwr;
  const float* bei = be + i * Ptwr;
  void* outv = i ? outb : outa;

  const int t = threadIdx.x;
  const int lane = t & 63, wv = t >> 6;
  const int m = lane & 15, quad = lane >> 4;
  const int tile0 = (blockIdx.x * 4 + wv) * RPW;

  f32x4 acc[RPW][8];
  #pragma unroll
  for (int rp = 0; rp < RPW; rp++)
    #pragma unroll
    for (int nt = 0; nt < 8; nt++) acc[rp][nt] = (f32x4){0.f, 0.f, 0.f, 0.f};

  #pragma unroll
  for (int c = 0; c < C1 + C2; c++) {
    bf16x8 a[RPW];
    #pragma unroll
    for (int rp = 0; rp < RPW; rp++) {
      const int r = (tile0 + rp) * 16 + m;
      a[rp] = (bf16x8){};
      if (r < Nrows) {
        if (c < C1) {
          if constexpr (CVT1) {
            const float* A1f = (const float*)A1;
            const float4* p4 = (const float4*)(A1f + (long)r * (C1 * 32) + c * 32 + quad * 8);
            float4 x0 = p4[0], x1 = p4[1];
            union { bf16x8 v; short s[8]; } u;
            u.s[0] = f2bf(x0.x); u.s[1] = f2bf(x0.y); u.s[2] = f2bf(x0.z); u.s[3] = f2bf(x0.w);
            u.s[4] = f2bf(x1.x); u.s[5] = f2bf(x1.y); u.s[6] = f2bf(x1.z); u.s[7] = f2bf(x1.w);
            a[rp] = u.v;
          } else {
            a[rp] = *(const bf16x8*)((const short*)A1 + (long)r * (C1 * 32) + c * 32 + quad * 8);
          }
        } else {
          a[rp] = *(const bf16x8*)(A2p + (long)r * (C2 * 32) + (c - C1) * 32 + quad * 8);
        }
      }
    }
    #pragma unroll
    for (int nt = 0; nt < 8; nt++) {
      bf16x8 b = *(const bf16x8*)(Wq + (long)(nt * 16 + m) * K + c * 32 + quad * 8);
      #pragma unroll
      for (int rp = 0; rp < RPW; rp++)
        acc[rp][nt] = __builtin_amdgcn_mfma_f32_16x16x32_bf16(a[rp], b, acc[rp][nt], 0, 0, 0);
    }
  }

  float bv[8], gv[8], bev[8];
  #pragma unroll
  for (int nt = 0; nt < 8; nt++) {
    bv[nt] = bi[nt * 16 + m]; gv[nt] = gi[nt * 16 + m]; bev[nt] = bei[nt * 16 + m];
  }

  #pragma unroll
  for (int rp = 0; rp < RPW; rp++) {
    float v[8][4];
    float s[4] = {0.f, 0.f, 0.f, 0.f}, q[4] = {0.f, 0.f, 0.f, 0.f};
    #pragma unroll
    for (int nt = 0; nt < 8; nt++) {
      #pragma unroll
      for (int j = 0; j < 4; j++) {
        float x = fmaxf(acc[rp][nt][j] + bv[nt], 0.f);
        v[nt][j] = x; s[j] += x; q[j] = fmaf(x, x, q[j]);
      }
    }
    #pragma unroll
    for (int mask = 1; mask <= 8; mask <<= 1) {
      #pragma unroll
      for (int j = 0; j < 4; j++) {
        s[j] += __shfl_xor(s[j], mask, 64);
        q[j] += __shfl_xor(q[j], mask, 64);
      }
    }
    #pragma unroll
    for (int j = 0; j < 4; j++) {
      const int row = (tile0 + rp) * 16 + quad * 4 + j;
      if (row < Nrows) {
        float mean = s[j] * (1.f / HH);
        float var = q[j] * (1.f / HH) - mean * mean;
        float inv = rsqrtf(fmaxf(var, 0.f) + 1e-5f);
        #pragma unroll
        for (int nt = 0; nt < 8; nt++) {
          float o = (v[nt][j] - mean) * inv * gv[nt] + bev[nt];
          if constexpr (F32OUT)
            ((float*)outv + i * Otwr)[(long)row * HH + nt * 16 + m] = o;
          else
            ((short*)outv + i * Otwr)[(long)row * HH + nt * 16 + m] = f2bf(o);
        }
      }
    }
  }
}

// ---------------------------------------------------------------------------
// Graph structure build: both towers in one pass; col holds GLOBAL row index.
// ---------------------------------------------------------------------------
__global__ void fill_kernel(const int* __restrict__ tcr_edge,
                            const int* __restrict__ pep_edge,
                            int* __restrict__ fil, int* __restrict__ col) {
  const int tower = blockIdx.y;
  const int e = blockIdx.x * 256 + threadIdx.x;
  if (e < EE) {
    const int* edge = tower ? pep_edge : tcr_edge;
    int gd = tower * NN + edge[EE + e];
    int gs = tower * NN + edge[e];
    int pos = atomicAdd(&fil[gd], 1);
    if (pos < SLOTS) col[(long)gd * SLOTS + pos] = gs;
  }
}

__global__ void invdeg_kernel(const int* __restrict__ cnt, float* __restrict__ invdeg) {
  const int n = blockIdx.x * 256 + threadIdx.x;
  if (n < 2 * NN) invdeg[n] = 1.f / fmaxf((float)cnt[n], 1.f);
}

// Mean neighbor aggregation over bf16 h (both towers): one node per wave,
// 2 cols/lane, 8-deep unroll for MLP (gather is L3-latency-bound).
__global__ __launch_bounds__(256) void agg_kernel(
    const short* __restrict__ h, const int* __restrict__ col,
    const int* __restrict__ cnt, const float* __restrict__ invdeg,
    short* __restrict__ agg)
{
  const int node = blockIdx.x * 4 + (threadIdx.x >> 6);
  const int lane = threadIdx.x & 63;
  if (node >= 2 * NN) return;
  const int d = min(cnt[node], SLOTS);
  const int* cl = col + (long)node * SLOTS;
  const unsigned* h32 = (const unsigned*)h;

  float s0 = 0.f, s1 = 0.f, t0 = 0.f, t1 = 0.f;
  float u0 = 0.f, u1 = 0.f, w0 = 0.f, w1 = 0.f;
  int t = 0;
  for (; t + 8 <= d; t += 8) {
    int4 i0 = *(const int4*)(cl + t);
    int4 i1 = *(const int4*)(cl + t + 4);
    unsigned v0 = h32[(long)i0.x * 64 + lane];
    unsigned v1 = h32[(long)i0.y * 64 + lane];
    unsigned v2 = h32[(long)i0.z * 64 + lane];
    unsigned v3 = h32[(long)i0.w * 64 + lane];
    unsigned v4 = h32[(long)i1.x * 64 + lane];
    unsigned v5 = h32[(long)i1.y * 64 + lane];
    unsigned v6 = h32[(long)i1.z * 64 + lane];
    unsigned v7 = h32[(long)i1.w * 64 + lane];
    s0 += lo16(v0); s1 += hi16(v0);
    t0 += lo16(v1); t1 += hi16(v1);
    u0 += lo16(v2); u1 += hi16(v2);
    w0 += lo16(v3); w1 += hi16(v3);
    s0 += lo16(v4); s1 += hi16(v4);
    t0 += lo16(v5); t1 += hi16(v5);
    u0 += lo16(v6); u1 += hi16(v6);
    w0 += lo16(v7); w1 += hi16(v7);
  }
  if (t + 4 <= d) {
    int4 i0 = *(const int4*)(cl + t);
    unsigned v0 = h32[(long)i0.x * 64 + lane];
    unsigned v1 = h32[(long)i0.y * 64 + lane];
    unsigned v2 = h32[(long)i0.z * 64 + lane];
    unsigned v3 = h32[(long)i0.w * 64 + lane];
    s0 += lo16(v0); s1 += hi16(v0);
    t0 += lo16(v1); t1 += hi16(v1);
    u0 += lo16(v2); u1 += hi16(v2);
    w0 += lo16(v3); w1 += hi16(v3);
    t += 4;
  }
  for (; t < d; t++) {
    unsigned v0 = h32[(long)cl[t] * 64 + lane];
    s0 += lo16(v0); s1 += hi16(v0);
  }
  float a0 = (s0 + t0) + (u0 + w0);
  float a1 = (s1 + t1) + (u1 + w1);
  const float inv = invdeg[node];
  unsigned o = ((unsigned)(unsigned short)f2bf(a1 * inv) << 16) |
               (unsigned)(unsigned short)f2bf(a0 * inv);
  ((unsigned*)(agg + (long)node * HH))[lane] = o;
}

// Sorted-batch mean pooling over bf16 h: block per graph, grid.y = tower.
__global__ __launch_bounds__(128) void pool_kernel(
    const short* __restrict__ hbase, const int* __restrict__ tcr_batch,
    const int* __restrict__ pep_batch, float* __restrict__ pooledbase)
{
  const int tower = blockIdx.y;
  const short* h = hbase + (long)tower * NN * HH;
  const int* batch = tower ? pep_batch : tcr_batch;
  float* pooled = pooledbase + (long)tower * BB * HH;
  const int b = blockIdx.x;
  const int j = threadIdx.x;
  int l = 0, r = NN;
  while (l < r) { int mid = (l + r) >> 1; if (batch[mid] < b) l = mid + 1; else r = mid; }
  const int lo = l;
  r = NN;
  while (l < r) { int mid = (l + r) >> 1; if (batch[mid] <= b) l = mid + 1; else r = mid; }
  const int hi = l;
  float s = 0.f;
  for (int n2 = lo; n2 < hi; n2++) s += bf2f(h[(long)n2 * HH + j]);
  pooled[(long)b * HH + j] = s / fmaxf((float)(hi - lo), 1.f);
}

// ---------------------------------------------------------------------------
// Binary head: feat=[tcr,pep,|t-p|,t*p] (512) -> relu(@W1+b1) (256) -> @W2+b2
// ---------------------------------------------------------------------------
__global__ __launch_bounds__(256) void head_kernel(
    const float* __restrict__ tcr, const float* __restrict__ pep,
    const float* __restrict__ W1, const float* __restrict__ b1,
    const float* __restrict__ W2, const float* __restrict__ b2,
    float* __restrict__ logits)
{
  __shared__ float feat[4][512];
  __shared__ float hid[4][256];
  __shared__ float red[4][4][2];
  const int t = threadIdx.x;
  const long r0 = (long)blockIdx.x * 4;
  for (int idx = t; idx < 4 * 128; idx += 256) {
    int r = idx >> 7, c = idx & 127;
    float a = tcr[(r0 + r) * HH + c], p = pep[(r0 + r) * HH + c];
    feat[r][c] = a; feat[r][128 + c] = p;
    feat[r][256 + c] = fabsf(a - p); feat[r][384 + c] = a * p;
  }
  __syncthreads();
  float acc[4];
  const float b1t = b1[t];
  #pragma unroll
  for (int r = 0; r < 4; r++) acc[r] = b1t;
  for (int k4 = 0; k4 < 128; k4++) {
    const int k = k4 * 4;
    float w0 = W1[(k + 0) * 256 + t], w1v = W1[(k + 1) * 256 + t];
    float w2v = W1[(k + 2) * 256 + t], w3v = W1[(k + 3) * 256 + t];
    #pragma unroll
    for (int r = 0; r < 4; r++) {
      float4 fv = ((const float4*)&feat[r][0])[k4];
      acc[r] = fmaf(fv.x, w0, acc[r]); acc[r] = fmaf(fv.y, w1v, acc[r]);
      acc[r] = fmaf(fv.z, w2v, acc[r]); acc[r] = fmaf(fv.w, w3v, acc[r]);
    }
  }
  #pragma unroll
  for (int r = 0; r < 4; r++) hid[r][t] = fmaxf(acc[r], 0.f);
  __syncthreads();
  const int wv = t >> 6, ln = t & 63;
  float w2c0 = W2[t * 2 + 0], w2c1 = W2[t * 2 + 1];
  #pragma unroll
  for (int r = 0; r < 4; r++) {
    float v0 = hid[r][t] * w2c0, v1 = hid[r][t] * w2c1;
    #pragma unroll
    for (int off = 32; off >= 1; off >>= 1) {
      v0 += __shfl_xor(v0, off, 64);
      v1 += __shfl_xor(v1, off, 64);
    }
    if (ln == 0) { red[wv][r][0] = v0; red[wv][r][1] = v1; }
  }
  __syncthreads();
  if (t < 8) {
    int r = t >> 1, c = t & 1;
    float S = red[0][r][c] + red[1][r][c] + red[2][r][c] + red[3][r][c] + b2[c];
    logits[(r0 + r) * 2 + c] = S;
  }
}

// ---------------------------------------------------------------------------
extern "C" void kernel_launch(void* const* d_in, const int* in_sizes, int n_in,
                              void* d_out, int out_size, void* d_ws, size_t ws_size,
                              hipStream_t stream)
{
  (void)in_sizes; (void)n_in; (void)out_size; (void)ws_size;
  const float* tcr_seq = (const float*)d_in[0];
  const float* pep_seq = (const float*)d_in[1];
  const float* tcr_x   = (const float*)d_in[2];
  const float* pep_x   = (const float*)d_in[3];
  const int*   tcr_edge = (const int*)d_in[4];
  const int*   pep_edge = (const int*)d_in[5];
  const int*   tcr_batch = (const int*)d_in[6];
  const int*   pep_batch = (const int*)d_in[7];
  const float* seq_W  = (const float*)d_in[8];
  const float* seq_b  = (const float*)d_in[9];
  const float* seq_g  = (const float*)d_in[10];
  const float* seq_be = (const float*)d_in[11];
  const float* gin_W  = (const float*)d_in[12];
  const float* gin_b  = (const float*)d_in[13];
  const float* gin_g  = (const float*)d_in[14];
  const float* gin_be = (const float*)d_in[15];
  const float* gl_self_W = (const float*)d_in[16];
  const float* gl_self_b = (const float*)d_in[17];
  const float* gl_nei_W  = (const float*)d_in[18];
  const float* gl_nei_b  = (const float*)d_in[19];
  const float* gl_g  = (const float*)d_in[20];
  const float* gl_be = (const float*)d_in[21];
  const float* gout_W  = (const float*)d_in[22];
  const float* gout_b  = (const float*)d_in[23];
  const float* gout_g  = (const float*)d_in[24];
  const float* gout_be = (const float*)d_in[25];
  const float* fuse_W  = (const float*)d_in[26];
  const float* fuse_b  = (const float*)d_in[27];
  const float* fuse_g  = (const float*)d_in[28];
  const float* fuse_be = (const float*)d_in[29];
  const float* bh_W1 = (const float*)d_in[30];
  const float* bh_b1 = (const float*)d_in[31];
  const float* bh_W2 = (const float*)d_in[32];
  const float* bh_b2 = (const float*)d_in[33];

  float* out = (float*)d_out;
  const long BH = (long)BB * HH;
  float* o_log = out;
  float* o_zts = out + BB * 2;
  float* o_ztg = o_zts + BH;
  float* o_zps = o_ztg + BH;
  float* o_zpg = o_zps + BH;
  float* o_tcr = o_zpg + BH;
  float* o_pep = o_tcr + BH;

  char* w = (char*)d_ws;
  short* hbuf   = (short*)w; w += (long)2 * NN * HH * 2;   // h (bf16), both towers
  short* abuf   = (short*)w; w += (long)2 * NN * HH * 2;   // agg (bf16)
  int*   col    = (int*)w;   w += (long)2 * NN * SLOTS * 4;
  int*   fil    = (int*)w;   w += (long)2 * NN * 4;        // degree
  float* invdeg = (float*)w; w += (long)2 * NN * 4;
  float* pooled = (float*)w; w += (long)2 * BB * HH * 4;
  short* bW_seq = (short*)w; w += (long)SEQ_ELEMS * 2;
  short* bW_gin = (short*)w; w += (long)GIN_ELEMS * 2;
  short* bW_gl  = (short*)w; w += (long)GL_ELEMS * 2;
  float* biasb  = (float*)w; w += (long)6 * 128 * 4;

  // 0. pack weights to bf16 [n][k] fragments
  pack_kernel<<<(SEQ_ELEMS + GIN_ELEMS + GL_ELEMS + 255) / 256, 256, 0, stream>>>(
      seq_W, gin_W, gl_self_W, gl_nei_W, gl_self_b, gl_nei_b,
      bW_seq, bW_gin, bW_gl, biasb);

  // graph structure (both towers)
  hipMemsetAsync(fil, 0, 2 * NN * 4, stream);
  fill_kernel<<<dim3(EE / 256, 2), 256, 0, stream>>>(tcr_edge, pep_edge, fil, col);
  invdeg_kernel<<<(2 * NN + 255) / 256, 256, 0, stream>>>(fil, invdeg);

  // 1. seq towers: MFMA, f32-in (cvt), f32-out, K=1024
  mfma_ln_k<32, 0, true, true, 1><<<dim3(BB / 64, 2), 256, 0, stream>>>(
      tcr_seq, pep_seq, bW_seq /*dummy A2*/, 0,
      bW_seq, (long)128 * 1024,
      seq_b, seq_g, seq_be, HH,
      o_zts, o_zps, 0, BB);

  // 2. gin (both towers): K=64, f32-in (cvt), bf16-out, RPW=2
  const int GUP = (NN + 127) / 128;   // 782 blocks, 128 rows each
  mfma_ln_k<2, 0, true, false, 2><<<dim3(GUP, 2), 256, 0, stream>>>(
      tcr_x, pep_x, bW_gin /*dummy A2*/, 0,
      bW_gin, (long)128 * 64,
      gin_b, gin_g, gin_be, HH,
      hbuf, hbuf, (long)NN * HH, NN);

  // 3. graph layers (both towers per dispatch)
  for (int l = 0; l < LL; l++) {
    agg_kernel<<<(2 * NN + 3) / 4, 256, 0, stream>>>(hbuf, col, fil, invdeg, abuf);
    mfma_ln_k<4, 4, false, false, 2><<<dim3(GUP, 2), 256, 0, stream>>>(
        hbuf, hbuf + (long)NN * HH, abuf, (long)NN * HH,
        bW_gl + (long)l * 128 * 256, (long)LL * 128 * 256,
        biasb + l * HH, gl_g + l * HH, gl_be + l * HH, (long)LL * HH,
        hbuf, hbuf, (long)NN * HH, NN);
  }

  // 4. pool + gout (both towers)
  pool_kernel<<<dim3(BB, 2), 128, 0, stream>>>(hbuf, tcr_batch, pep_batch, pooled);
  ln_gemm_A<HH, 0, 8><<<dim3(BB / 8, 2), 128, 0, stream>>>(
      pooled, pooled + BH, nullptr, nullptr,
      gout_W, (long)HH * HH, gout_b, gout_g, gout_be, HH,
      o_ztg, o_zpg);

  // 5. fuse towers (both at once)
  ln_gemm_A<HH, HH, 8><<<dim3(BB / 8, 2), 128, 0, stream>>>(
      o_zts, o_zps, o_ztg, o_zpg,
      fuse_W, (long)2 * HH * HH, fuse_b, fuse_g, fuse_be, HH, o_tcr, o_pep);

  // 6. binary head
  head_kernel<<<BB / 4, 256, 0, stream>>>(
      o_tcr, o_pep, bh_W1, bh_b1, bh_W2, bh_b2, o_log);
}